// Round 4
// baseline (320.955 us; speedup 1.0000x reference)
//
#include <hip/hip_runtime.h>
#include <hip/hip_cooperative_groups.h>
#include <math.h>

namespace cg = cooperative_groups;

// x: (256, 224, 224) f32.
#define HW    50176
#define NV4   12544          // float4 per row
#define ROWS  256
#define CPR   4              // chunks (blocks) per row
#define CV4   3136           // float4 per chunk = 12*256 + 64
#define TPB   256
#define NBLK  (ROWS * CPR)   // 1024 blocks = 4 blocks/CU over 256 CUs

typedef float floatx4 __attribute__((ext_vector_type(4)));

// ws layout: float mins[1024] @0 ; double sums[1024] @4096 ; double sumls[1024] @12288
#define WS_MIN(ws)  ((float*)(ws))
#define WS_SUM(ws)  ((double*)((char*)(ws) + 4096))
#define WS_SL(ws)   ((double*)((char*)(ws) + 12288))

__device__ __forceinline__ float waveMin(float v) {
#pragma unroll
    for (int o = 32; o > 0; o >>= 1) v = fminf(v, __shfl_down(v, o, 64));
    return v;
}
__device__ __forceinline__ double waveSumD(double v) {
#pragma unroll
    for (int o = 32; o > 0; o >>= 1) v += __shfl_down(v, o, 64);
    return v;
}

__device__ __forceinline__ float digamma_f(float x) {
    float r = 0.0f;
    while (x < 6.0f) { r -= 1.0f / x; x += 1.0f; }
    float f = 1.0f / (x * x);
    float ser = f * (1.0f/12.0f - f * (1.0f/120.0f - f * (1.0f/252.0f - f * (1.0f/240.0f - f * (1.0f/132.0f)))));
    return r + logf(x) - 0.5f / x - ser;
}
__device__ __forceinline__ float trigamma_ref(float x) {
    float z = x + 1.0f, zz = z * z;
    float a = 0.2f - 1.0f / (7.0f * zz);
    float b = 1.0f - a / zz;
    float c = 1.0f + b / (3.0f * z);
    float d = 1.0f + c / (2.0f * z);
    return d / z + 1.0f / (x * x);
}

// ts = raw sum of x over row, tl = sum of log(x - rmin + 2e-7) over row.
// par out: {k, invth, c0..c7}
__device__ __forceinline__ void solve_params(double ts, double tl, float rmin, float* par) {
    ts -= (double)HW * ((double)rmin - 2e-7);     // shift: xm = x - rmin + 2e-7
    const double meand = ts / (double)HW;
    float s = (float)(log(meand) - tl / (double)HW);

    float s3 = s - 3.0f;
    float rt = sqrtf(s3 * s3 + 24.0f * s);
    float k  = (3.0f - s + rt) / (12.0f * s) + 1e-7f;
    for (int it = 0; it < 10; ++it) {
        float nm = logf(k) - digamma_f(k) - s;
        float dn = 1.0f / k - trigamma_ref(k);
        k = k - nm / dn;
    }
    if (k < 1e-7f) k = 1e-7f;   // NaN falls through both (np.clip semantics)
    if (k > 18.0f) k = 18.0f;

    const double CH[8] = {676.5203681218851, -1259.1392167224028, 771.3234287776531,
                          -176.6150291621406, 12.507343278686905, -0.13857109526572012,
                          9.984369578019572e-06, 1.5056327351493116e-07};
    double z = (double)k;
    double acc = 0.9999999999998099;
#pragma unroll
    for (int i = 0; i < 8; ++i) acc += CH[i] / (z + (double)(i + 1));
    double t = z + 7.5;
    double g = 2.5066282746310002 * exp((z + 0.5) * log(t) - t) * acc / z;  // Gamma(k)

    par[0] = k;
    par[1] = (float)((double)k / meand);          // 1/theta
    double den = g * z;
    par[2] = (float)(1.0 / den);
#pragma unroll
    for (int j = 1; j < 8; ++j) {
        den *= (z + (double)j);
        par[2 + j] = (float)(1.0 / den);
    }
}

__device__ __forceinline__ float apply_one(float e, float rmin, float invth,
                                           float kk, const float* c) {
    float xq = (e - rmin + 1e-7f) * invth;        // single eps: matches ref's xf/th
    float p = fmaf(c[7], xq, c[6]);
    p = fmaf(p, xq, c[5]);
    p = fmaf(p, xq, c[4]);
    p = fmaf(p, xq, c[3]);
    p = fmaf(p, xq, c[2]);
    p = fmaf(p, xq, c[1]);
    p = fmaf(p, xq, c[0]);
    float y = __expf(fmaf(kk, __logf(xq), -xq)) * p;
    return isfinite(y) ? y : 0.0f;
}

// ==================== cooperative single-pass kernel ====================
__global__ void __launch_bounds__(TPB, 4)
gamma_coop(const float* __restrict__ x, float* __restrict__ out, void* __restrict__ ws) {
    cg::grid_group grid = cg::this_grid();
    const int bid  = blockIdx.x;
    const int row  = bid >> 2;
    const int chnk = bid & 3;
    const int tid  = threadIdx.x;
    const int wid  = tid >> 6, lane = tid & 63;
    const bool extra = (tid < (CV4 - 12 * TPB));   // tid < 64 holds a 13th float4

    const size_t base = (size_t)row * NV4 + (size_t)chnk * CV4;
    const float4* __restrict__ xr = (const float4*)x + base;

    // load entire chunk into registers (<= 52 VGPR)
    float4 v[13];
#pragma unroll
    for (int j = 0; j < 12; ++j) v[j] = xr[j * TPB + tid];
    v[12] = extra ? xr[12 * TPB + tid]
                  : make_float4(INFINITY, INFINITY, INFINITY, INFINITY);

    // ---- phase A: partial min + raw sum ----
    float pmin = INFINITY, psum = 0.0f;
#pragma unroll
    for (int j = 0; j < 13; ++j) {
        pmin = fminf(pmin, fminf(fminf(v[j].x, v[j].y), fminf(v[j].z, v[j].w)));
        if (j < 12 || extra) psum += (v[j].x + v[j].y) + (v[j].z + v[j].w);
    }
    pmin = waveMin(pmin);
    double dsum = waveSumD((double)psum);

    __shared__ float  smin[4];
    __shared__ double sacc[4];
    __shared__ float  spar[10];
    if (lane == 0) { smin[wid] = pmin; sacc[wid] = dsum; }
    __syncthreads();
    if (tid == 0) {
        WS_MIN(ws)[bid] = fminf(fminf(smin[0], smin[1]), fminf(smin[2], smin[3]));
        WS_SUM(ws)[bid] = (sacc[0] + sacc[1]) + (sacc[2] + sacc[3]);
    }
    grid.sync();

    // ---- phase B: row min, then partial sumlog (from registers) ----
    const float* wm = WS_MIN(ws) + (row << 2);
    const float rmin = fminf(fminf(wm[0], wm[1]), fminf(wm[2], wm[3]));

    float psl = 0.0f;
#pragma unroll
    for (int j = 0; j < 13; ++j) {
        if (j < 12 || extra) {
            psl += (__logf(v[j].x - rmin + 1e-7f + 1e-7f) + __logf(v[j].y - rmin + 1e-7f + 1e-7f))
                 + (__logf(v[j].z - rmin + 1e-7f + 1e-7f) + __logf(v[j].w - rmin + 1e-7f + 1e-7f));
        }
    }
    double dsl = waveSumD((double)psl);
    if (lane == 0) sacc[wid] = dsl;
    __syncthreads();
    if (tid == 0)
        WS_SL(ws)[bid] = (sacc[0] + sacc[1]) + (sacc[2] + sacc[3]);
    grid.sync();

    // ---- phase C: redundant per-block solve, broadcast, apply ----
    if (tid == 0) {
        const double* su = WS_SUM(ws) + (row << 2);
        const double* sl = WS_SL(ws)  + (row << 2);
        double ts = (su[0] + su[1]) + (su[2] + su[3]);
        double tl = (sl[0] + sl[1]) + (sl[2] + sl[3]);
        solve_params(ts, tl, rmin, spar);
    }
    __syncthreads();
    const float kk = spar[0], invth = spar[1];
    float c[8];
#pragma unroll
    for (int i = 0; i < 8; ++i) c[i] = spar[2 + i];

    floatx4* __restrict__ yr = (floatx4*)out + base;
#pragma unroll
    for (int j = 0; j < 13; ++j) {
        if (j < 12 || extra) {
            floatx4 o;
            o.x = apply_one(v[j].x, rmin, invth, kk, c);
            o.y = apply_one(v[j].y, rmin, invth, kk, c);
            o.z = apply_one(v[j].z, rmin, invth, kk, c);
            o.w = apply_one(v[j].w, rmin, invth, kk, c);
            __builtin_nontemporal_store(o, yr + j * TPB + tid);
        }
    }
}

// ==================== fallback (non-cooperative) 3-kernel path ====================
__global__ void __launch_bounds__(TPB, 4)
k_phaseA(const float* __restrict__ x, void* __restrict__ ws) {
    const int bid = blockIdx.x, tid = threadIdx.x;
    const int row = bid >> 2, chnk = bid & 3;
    const int wid = tid >> 6, lane = tid & 63;
    const bool extra = (tid < (CV4 - 12 * TPB));
    const float4* __restrict__ xr = (const float4*)x + (size_t)row * NV4 + (size_t)chnk * CV4;

    float pmin = INFINITY, psum = 0.0f;
#pragma unroll
    for (int j = 0; j < 13; ++j) {
        if (j < 12 || extra) {
            float4 v = xr[j * TPB + tid];
            pmin = fminf(pmin, fminf(fminf(v.x, v.y), fminf(v.z, v.w)));
            psum += (v.x + v.y) + (v.z + v.w);
        }
    }
    pmin = waveMin(pmin);
    double dsum = waveSumD((double)psum);
    __shared__ float  smin[4];
    __shared__ double sacc[4];
    if (lane == 0) { smin[wid] = pmin; sacc[wid] = dsum; }
    __syncthreads();
    if (tid == 0) {
        WS_MIN(ws)[bid] = fminf(fminf(smin[0], smin[1]), fminf(smin[2], smin[3]));
        WS_SUM(ws)[bid] = (sacc[0] + sacc[1]) + (sacc[2] + sacc[3]);
    }
}

__global__ void __launch_bounds__(TPB, 4)
k_phaseB(const float* __restrict__ x, void* __restrict__ ws) {
    const int bid = blockIdx.x, tid = threadIdx.x;
    const int row = bid >> 2, chnk = bid & 3;
    const int wid = tid >> 6, lane = tid & 63;
    const bool extra = (tid < (CV4 - 12 * TPB));
    const float* wm = WS_MIN(ws) + (row << 2);
    const float rmin = fminf(fminf(wm[0], wm[1]), fminf(wm[2], wm[3]));
    const float4* __restrict__ xr = (const float4*)x + (size_t)row * NV4 + (size_t)chnk * CV4;

    float psl = 0.0f;
#pragma unroll
    for (int j = 0; j < 13; ++j) {
        if (j < 12 || extra) {
            float4 v = xr[j * TPB + tid];
            psl += (__logf(v.x - rmin + 1e-7f + 1e-7f) + __logf(v.y - rmin + 1e-7f + 1e-7f))
                 + (__logf(v.z - rmin + 1e-7f + 1e-7f) + __logf(v.w - rmin + 1e-7f + 1e-7f));
        }
    }
    double dsl = waveSumD((double)psl);
    __shared__ double sacc[4];
    if (lane == 0) sacc[wid] = dsl;
    __syncthreads();
    if (tid == 0) WS_SL(ws)[bid] = (sacc[0] + sacc[1]) + (sacc[2] + sacc[3]);
}

__global__ void __launch_bounds__(TPB, 4)
k_phaseC(const float* __restrict__ x, float* __restrict__ out, void* __restrict__ ws) {
    const int bid = blockIdx.x, tid = threadIdx.x;
    const int row = bid >> 2, chnk = bid & 3;
    const bool extra = (tid < (CV4 - 12 * TPB));
    const float* wm = WS_MIN(ws) + (row << 2);
    const float rmin = fminf(fminf(wm[0], wm[1]), fminf(wm[2], wm[3]));

    __shared__ float spar[10];
    if (tid == 0) {
        const double* su = WS_SUM(ws) + (row << 2);
        const double* sl = WS_SL(ws)  + (row << 2);
        double ts = (su[0] + su[1]) + (su[2] + su[3]);
        double tl = (sl[0] + sl[1]) + (sl[2] + sl[3]);
        solve_params(ts, tl, rmin, spar);
    }
    __syncthreads();
    const float kk = spar[0], invth = spar[1];
    float c[8];
#pragma unroll
    for (int i = 0; i < 8; ++i) c[i] = spar[2 + i];

    const size_t base = (size_t)row * NV4 + (size_t)chnk * CV4;
    const float4* __restrict__ xr = (const float4*)x + base;
    floatx4* __restrict__ yr = (floatx4*)out + base;
#pragma unroll
    for (int j = 0; j < 13; ++j) {
        if (j < 12 || extra) {
            float4 v = xr[j * TPB + tid];
            floatx4 o;
            o.x = apply_one(v.x, rmin, invth, kk, c);
            o.y = apply_one(v.y, rmin, invth, kk, c);
            o.z = apply_one(v.z, rmin, invth, kk, c);
            o.w = apply_one(v.w, rmin, invth, kk, c);
            __builtin_nontemporal_store(o, yr + j * TPB + tid);
        }
    }
}

extern "C" void kernel_launch(void* const* d_in, const int* in_sizes, int n_in,
                              void* d_out, int out_size, void* d_ws, size_t ws_size,
                              hipStream_t stream) {
    const float* x = (const float*)d_in[0];
    float* out = (float*)d_out;
    void* ws = d_ws;

    void* args[] = {(void*)&x, (void*)&out, (void*)&ws};
    hipError_t err = hipLaunchCooperativeKernel((const void*)gamma_coop,
                                                dim3(NBLK), dim3(TPB), args, 0, stream);
    if (err != hipSuccess) {
        (void)hipGetLastError();   // clear sticky error; fall back to split pipeline
        k_phaseA<<<dim3(NBLK), dim3(TPB), 0, stream>>>(x, ws);
        k_phaseB<<<dim3(NBLK), dim3(TPB), 0, stream>>>(x, ws);
        k_phaseC<<<dim3(NBLK), dim3(TPB), 0, stream>>>(x, out, ws);
    }
}

// Round 5
// 110.540 us; speedup vs baseline: 2.9035x; 2.9035x over previous
//
#include <hip/hip_runtime.h>
#include <math.h>

// x: (256, 224, 224) f32.  One block per row, whole row in registers.
#define HW   50176   // 224*224
#define NV4  12544   // float4 per row;  12544 = 12*1024 + 256
#define TPB  1024

typedef float floatx4 __attribute__((ext_vector_type(4)));

__device__ __forceinline__ float waveMin(float v) {
#pragma unroll
    for (int o = 32; o > 0; o >>= 1) v = fminf(v, __shfl_down(v, o, 64));
    return v;
}
__device__ __forceinline__ double waveSumD(double v) {
#pragma unroll
    for (int o = 32; o > 0; o >>= 1) v += __shfl_down(v, o, 64);
    return v;
}

__device__ __forceinline__ float digamma_f(float x) {
    // shift to >= 6, asymptotic series; matches jax digamma to ~1e-6
    float r = 0.0f;
#pragma unroll 6
    for (int i = 0; i < 6; ++i) {
        if (x < 6.0f) { r -= __fdividef(1.0f, x); x += 1.0f; }
    }
    float f = __fdividef(1.0f, x * x);
    float ser = f * (1.0f/12.0f - f * (1.0f/120.0f - f * (1.0f/252.0f - f * (1.0f/240.0f - f * (1.0f/132.0f)))));
    return r + logf(x) - 0.5f * __fdividef(1.0f, x) - ser;
}
__device__ __forceinline__ float trigamma_ref(float x) {
    float z = x + 1.0f, zz = z * z;
    float a = 0.2f - __fdividef(1.0f, 7.0f * zz);
    float b = 1.0f - __fdividef(a, zz);
    float c = 1.0f + __fdividef(b, 3.0f * z);
    float d = 1.0f + __fdividef(c, 2.0f * z);
    return __fdividef(d, z) + __fdividef(1.0f, x * x);
}

__global__ void __launch_bounds__(TPB)
gamma_norm2d(const float* __restrict__ x, float* __restrict__ out) {
    const int row = blockIdx.x;
    const int tid = threadIdx.x;
    const float4* __restrict__ xr = (const float4*)(x + (size_t)row * HW);

    const bool extra = (tid < (NV4 - 12 * TPB));  // tid < 256 holds a 13th float4

    // ---- load entire row into registers (13 float4 / thread) ----
    float4 v[13];
#pragma unroll
    for (int j = 0; j < 12; ++j) v[j] = xr[tid + j * TPB];
    v[12] = extra ? xr[tid + 12 * TPB]
                  : make_float4(INFINITY, INFINITY, INFINITY, INFINITY);

    // ---- phase A: row min + raw sum ----
    float pmin = INFINITY, psum = 0.0f;
#pragma unroll
    for (int j = 0; j < 13; ++j) {
        pmin = fminf(pmin, fminf(fminf(v[j].x, v[j].y), fminf(v[j].z, v[j].w)));
        if (j < 12 || extra) psum += (v[j].x + v[j].y) + (v[j].z + v[j].w);
    }
    pmin = waveMin(pmin);
    double dsum = waveSumD((double)psum);

    __shared__ float  smin[16];
    __shared__ double sacc[16];
    __shared__ float  sparams[3];   // rmin, k, invth
    __shared__ float  scoef[8];

    const int wid = tid >> 6, lane = tid & 63;
    if (lane == 0) { smin[wid] = pmin; sacc[wid] = dsum; }
    __syncthreads();
    if (tid == 0) {
        float mm = smin[0];
        for (int i = 1; i < 16; ++i) mm = fminf(mm, smin[i]);
        sparams[0] = mm;
    }
    __syncthreads();
    const float rmin = sparams[0];

    // ---- phase B: sum of log(x - rmin + 2e-7) from registers ----
    float psl = 0.0f;
#pragma unroll
    for (int j = 0; j < 13; ++j) {
        if (j < 12 || extra) {
            psl += (__logf(v[j].x - rmin + 1e-7f + 1e-7f) + __logf(v[j].y - rmin + 1e-7f + 1e-7f))
                 + (__logf(v[j].z - rmin + 1e-7f + 1e-7f) + __logf(v[j].w - rmin + 1e-7f + 1e-7f));
        }
    }
    double dsl = waveSumD((double)psl);
    __shared__ double ssl[16];
    if (lane == 0) ssl[wid] = dsl;
    __syncthreads();

    // ---- per-row scalar solve (thread 0), all-f32 transcendentals ----
    if (tid == 0) {
        double ts = 0.0, tl = 0.0;
        for (int i = 0; i < 16; ++i) { ts += sacc[i]; tl += ssl[i]; }
        // shift: xm = x - rmin + 2e-7 (sum is linear in the shift)
        ts -= (double)HW * ((double)rmin - 2e-7);
        const double meand = ts / (double)HW;
        float s = logf((float)meand) - (float)(tl / (double)HW);

        float s3 = s - 3.0f;
        float rt = sqrtf(s3 * s3 + 24.0f * s);
        float k  = __fdividef(3.0f - s + rt, 12.0f * s) + 1e-7f;
#pragma unroll
        for (int it = 0; it < 10; ++it) {
            float nm = logf(k) - digamma_f(k) - s;
            float dn = __fdividef(1.0f, k) - trigamma_ref(k);
            k -= __fdividef(nm, dn);
        }
        if (k < 1e-7f) k = 1e-7f;   // NaN falls through (np.clip semantics)
        if (k > 18.0f) k = 18.0f;

        // Lanczos Gamma(k): accumulator in f64 (cancellation), rest f32
        const double CH[8] = {676.5203681218851, -1259.1392167224028, 771.3234287776531,
                              -176.6150291621406, 12.507343278686905, -0.13857109526572012,
                              9.984369578019572e-06, 1.5056327351493116e-07};
        double acc = 0.9999999999998099;
#pragma unroll
        for (int i = 0; i < 8; ++i) acc += CH[i] / ((double)k + (double)(i + 1));
        float t  = k + 7.5f;
        float g  = __expf(fmaf(k + 0.5f, __logf(t), -t)) * 2.50662827463f * (float)acc / k; // Gamma(k)

        float den = g * k;                       // Gamma * k
        scoef[0] = __fdividef(1.0f, den);
#pragma unroll
        for (int j = 1; j < 8; ++j) {
            den *= (k + (float)j);
            scoef[j] = __fdividef(1.0f, den);
        }
        sparams[1] = k;
        sparams[2] = (float)((double)k / meand);   // 1/theta
    }
    __syncthreads();

    const float kk = sparams[1], invth = sparams[2];
    const float c0 = scoef[0], c1 = scoef[1], c2 = scoef[2], c3 = scoef[3];
    const float c4 = scoef[4], c5 = scoef[5], c6 = scoef[6], c7 = scoef[7];

    // ---- phase C: y = exp(k*ln(xq) - xq) * Horner(c, xq), nontemporal stores ----
    floatx4* __restrict__ yr = (floatx4*)(out + (size_t)row * HW);
#pragma unroll
    for (int j = 0; j < 13; ++j) {
        if (j < 12 || extra) {
            float e[4] = {v[j].x, v[j].y, v[j].z, v[j].w};
            floatx4 o;
#pragma unroll
            for (int q = 0; q < 4; ++q) {
                float xq = (e[q] - rmin + 1e-7f) * invth;
                float p = fmaf(c7, xq, c6);
                p = fmaf(p, xq, c5);
                p = fmaf(p, xq, c4);
                p = fmaf(p, xq, c3);
                p = fmaf(p, xq, c2);
                p = fmaf(p, xq, c1);
                p = fmaf(p, xq, c0);
                float y = __expf(fmaf(kk, __logf(xq), -xq)) * p;
                o[q] = isfinite(y) ? y : 0.0f;
            }
            __builtin_nontemporal_store(o, yr + tid + j * TPB);
        }
    }
}

extern "C" void kernel_launch(void* const* d_in, const int* in_sizes, int n_in,
                              void* d_out, int out_size, void* d_ws, size_t ws_size,
                              hipStream_t stream) {
    const float* x = (const float*)d_in[0];
    float* out = (float*)d_out;
    const int rows = in_sizes[0] / HW;   // 256
    gamma_norm2d<<<dim3(rows), dim3(TPB), 0, stream>>>(x, out);
}